// Round 3
// baseline (18.845 us; speedup 1.0000x reference)
//
#include <hip/hip_runtime.h>

#define HW 56
#define PLANE 3136     // 56*56
#define CH 64          // channels after pair-sum
#define CI 32          // output channels
#define WPAIRS 28      // float2 groups per row
#define P2 (HW*WPAIRS) // 1568 float2 pixel-groups per output channel

// ---------- kernel 1: t2 = x[0:64] + x[64:128], float4 ----------
__global__ __launch_bounds__(256) void pairsum_kernel(
    const float* __restrict__ x, float* __restrict__ t2)
{
    int idx = blockIdx.x * 256 + threadIdx.x;     // 50176 float4 groups, 196 blocks exact
    const float4* xa = (const float4*)x;
    const float4* xb = (const float4*)(x + CH * PLANE);
    float4 a = xa[idx], b = xb[idx];
    float4 r; r.x = a.x + b.x; r.y = a.y + b.y; r.z = a.z + b.z; r.w = a.w + b.w;
    ((float4*)t2)[idx] = r;
}

// ---------- kernel 2: conv over t2, 2 outputs (w0,w0+1) per thread ----------
// grid = (7, 32), block = 256; 7*256 = 1792 >= 1568
__global__ __launch_bounds__(256) void conv_kernel(
    const float* __restrict__ t2, const float* __restrict__ Wt, float* __restrict__ out)
{
    __shared__ float sW[CH * 3];
    const int i   = blockIdx.y;
    const int tid = threadIdx.x;
    if (tid < CH * 3) sW[tid] = Wt[i * (CH * 3) + tid];
    __syncthreads();

    const int p   = blockIdx.x * 256 + tid;
    const int pc  = (p < P2) ? p : (P2 - 1);
    const int h   = pc / WPAIRS;
    const int wp  = pc - h * WPAIRS;
    const int w0  = wp * 2;

    const bool v0 = (h > 0), v2 = (h < HW - 1);
    const int hm  = v0 ? h - 1 : 0;       // clamped, masked at end
    const int hp  = v2 ? h + 1 : HW - 1;

    const float* __restrict__ b0 = t2 + hm * HW + w0;
    const float* __restrict__ b1 = t2 + h  * HW + w0;
    const float* __restrict__ b2 = t2 + hp * HW + w0;

    float a0x = 0.f, a0y = 0.f, a1x = 0.f, a1y = 0.f, a2x = 0.f, a2y = 0.f;

    float2 R0[2][8], R1[2][8], R2[2][8];   // double-buffered: 8 channels x 3 rows in flight

    #pragma unroll
    for (int j = 0; j < 8; ++j) {
        const int o = j * PLANE;
        R0[0][j] = *(const float2*)(b0 + o);
        R1[0][j] = *(const float2*)(b1 + o);
        R2[0][j] = *(const float2*)(b2 + o);
    }

    #pragma unroll
    for (int ch = 0; ch < 8; ++ch) {
        const int cur = ch & 1, nxt = cur ^ 1;
        if (ch < 7) {
            #pragma unroll
            for (int j = 0; j < 8; ++j) {
                const int o = (ch * 8 + 8 + j) * PLANE;
                R0[nxt][j] = *(const float2*)(b0 + o);
                R1[nxt][j] = *(const float2*)(b1 + o);
                R2[nxt][j] = *(const float2*)(b2 + o);
            }
        }
        #pragma unroll
        for (int j = 0; j < 8; ++j) {
            const int c = ch * 8 + j;
            const float w0_ = sW[c * 3 + 0];
            const float w1_ = sW[c * 3 + 1];
            const float w2_ = sW[c * 3 + 2];
            a0x += R0[cur][j].x * w0_;  a0y += R0[cur][j].y * w0_;
            a1x += R1[cur][j].x * w1_;  a1y += R1[cur][j].y * w1_;
            a2x += R2[cur][j].x * w2_;  a2y += R2[cur][j].y * w2_;
        }
    }

    float accx = a1x, accy = a1y;
    if (v0) { accx += a0x; accy += a0y; }
    if (v2) { accx += a2x; accy += a2y; }

    if (p < P2) {
        // roll(+1, axis=w): value at w stored at w+1 (w0+1 <= 55 never wraps)
        float* orow = out + i * PLANE + h * HW;
        orow[w0 + 1] = accx;
        int ws2 = w0 + 2; if (ws2 == HW) ws2 = 0;
        orow[ws2] = accy;
    }
}

// ---------- fallback: R1 single-kernel (used only if ws too small) ----------
__global__ __launch_bounds__(256) void convshift_fb(
    const float* __restrict__ x, const float* __restrict__ Wt, float* __restrict__ out)
{
    __shared__ float sW[CH * 3];
    const int i   = blockIdx.y;
    const int tid = threadIdx.x;
    if (tid < CH * 3) sW[tid] = Wt[i * (CH * 3) + tid];
    __syncthreads();
    const int p  = blockIdx.x * 256 + tid;
    const int pc = (p < PLANE) ? p : (PLANE - 1);
    const int h  = pc / HW;
    const int w  = pc - h * HW;
    const int hm = (h > 0) ? h - 1 : 0;
    const int hp = (h < HW - 1) ? h + 1 : HW - 1;
    const bool v0 = (h > 0), v2 = (h < HW - 1);
    const float* xa = x + w;
    const float* xb = x + CH * PLANE + w;
    const int r0 = hm * HW, r1 = h * HW, r2 = hp * HW;
    float ca0 = 0.f, ca1 = 0.f, ca2 = 0.f, cb0 = 0.f, cb1 = 0.f, cb2 = 0.f;
    #pragma unroll 8
    for (int c = 0; c < CH; ++c) {
        const int o = c * PLANE;
        const float w0_ = sW[c * 3 + 0], w1_ = sW[c * 3 + 1], w2_ = sW[c * 3 + 2];
        ca0 += xa[o + r0] * w0_; cb0 += xb[o + r0] * w0_;
        ca1 += xa[o + r1] * w1_; cb1 += xb[o + r1] * w1_;
        ca2 += xa[o + r2] * w2_; cb2 += xb[o + r2] * w2_;
    }
    float acc = ca1 + cb1;
    if (v0) acc += ca0 + cb0;
    if (v2) acc += ca2 + cb2;
    if (p < PLANE) {
        int wst = w + 1; if (wst == HW) wst = 0;
        out[i * PLANE + h * HW + wst] = acc;
    }
}

extern "C" void kernel_launch(void* const* d_in, const int* in_sizes, int n_in,
                              void* d_out, int out_size, void* d_ws, size_t ws_size,
                              hipStream_t stream) {
    const float* x  = (const float*)d_in[0];   // (1,128,56,56) f32
    const float* Wt = (const float*)d_in[1];   // (32,64,3) f32
    float* out = (float*)d_out;                // (1,32,56,56) f32

    const size_t t2_bytes = (size_t)CH * PLANE * sizeof(float);  // 802816
    if (ws_size >= t2_bytes) {
        float* t2 = (float*)d_ws;
        hipLaunchKernelGGL(pairsum_kernel, dim3(196), dim3(256), 0, stream, x, t2);
        hipLaunchKernelGGL(conv_kernel, dim3(7, CI), dim3(256), 0, stream, t2, Wt, out);
    } else {
        hipLaunchKernelGGL(convshift_fb, dim3(13, CI), dim3(256), 0, stream, x, Wt, out);
    }
}